// Round 2
// baseline (349.483 us; speedup 1.0000x reference)
//
#include <hip/hip_runtime.h>

#define BB 64
#define CC 64
#define TT 4000

// ---- gram kernel geometry ----
#define SLABS 25
#define TSLAB (TT / SLABS)    // 160
#define TCH 80                // t-chunk staged in LDS
#define NCHUNK (TSLAB / TCH)  // 2
#define PITCH 84              // 80 + 4 pad: bank stride 84%32=20 -> rows ly*20 mod 32 all distinct

// ---- apply kernel geometry ----
#define TPB 128                       // t per block
#define NT2 ((TT + TPB - 1) / TPB)    // 32 tiles (last partially valid)

// ws layout (floats): G : BB*CC*CC  |  S : BB*CC
#define G_ELEMS ((size_t)BB * CC * CC)
#define S_ELEMS ((size_t)BB * CC)

__global__ __launch_bounds__(256)
void zero_ws_kernel(float* __restrict__ ws) {
    size_t n = G_ELEMS + S_ELEMS;
    size_t i = (size_t)blockIdx.x * blockDim.x + threadIdx.x;
    if (i * 4 + 3 < n) {
        *(float4*)(ws + i * 4) = make_float4(0.f, 0.f, 0.f, 0.f);
    } else {
        for (size_t k = i * 4; k < n; ++k) ws[k] = 0.f;
    }
}

// G[b][r][c] = sum_t x[b][r][t]*x[b][c][t]; S[b][c] = sum_t x[b][c][t]
// 4 waves per block; each wave computes the FULL 64x64 tile with 8x8/lane
// register tiles over a disjoint quarter of the t-chunk; atomic merge.
__global__ __launch_bounds__(256)
void gram_kernel(const float* __restrict__ x, float* __restrict__ G,
                 float* __restrict__ S) {
    __shared__ float xs[CC * PITCH];          // 21.5 KB
    const int b    = blockIdx.x / SLABS;
    const int slab = blockIdx.x % SLABS;
    const int t0   = slab * TSLAB;
    const int tid  = threadIdx.x;
    const int wave = tid >> 6;
    const int lane = tid & 63;
    const int lx = lane & 7, ly = lane >> 3;
    const float* xb = x + (size_t)b * CC * TT;

    float acc[8][8];
    #pragma unroll
    for (int i = 0; i < 8; ++i)
        #pragma unroll
        for (int j = 0; j < 8; ++j) acc[i][j] = 0.f;
    float rsum = 0.f;

    for (int ch = 0; ch < NCHUNK; ++ch) {
        const int tb = t0 + ch * TCH;
        __syncthreads();
        // stage 64 x 80 chunk (rows padded to pitch 84, still 16B-aligned)
        for (int idx = tid; idx < CC * (TCH / 4); idx += 256) {
            int c = idx / (TCH / 4);
            int p = idx - c * (TCH / 4);
            *(float4*)(xs + c * PITCH + 4 * p) =
                *(const float4*)(xb + c * TT + tb + 4 * p);
        }
        __syncthreads();
        // partial row sums: thread owns (row = tid&63, quarter = tid>>6)
        {
            int c = tid & 63, q = tid >> 6;
            const float* row = xs + c * PITCH + q * (TCH / 4);
            float s = 0.f;
            #pragma unroll
            for (int j = 0; j < TCH / 4; ++j) s += row[j];
            rsum += s;
        }
        // wave w handles tc = 4w + 16k, k=0..4 (disjoint t-quarters)
        #pragma unroll
        for (int k = 0; k < TCH / 16; ++k) {
            const int tc = 4 * wave + 16 * k;
            float4 bv[8];
            #pragma unroll
            for (int j = 0; j < 8; ++j)
                bv[j] = *(const float4*)(xs + (lx + 8 * j) * PITCH + tc);
            #pragma unroll
            for (int i = 0; i < 8; ++i) {
                float4 a = *(const float4*)(xs + (ly + 8 * i) * PITCH + tc);
                #pragma unroll
                for (int j = 0; j < 8; ++j)
                    acc[i][j] += a.x * bv[j].x + a.y * bv[j].y +
                                 a.z * bv[j].z + a.w * bv[j].w;
            }
        }
    }
    atomicAdd(S + b * CC + (tid & 63), rsum);
    float* Gb = G + (size_t)b * CC * CC;
    #pragma unroll
    for (int i = 0; i < 8; ++i)
        #pragma unroll
        for (int j = 0; j < 8; ++j)
            atomicAdd(Gb + (ly + 8 * i) * CC + lx + 8 * j, acc[i][j]);
}

// energy -> minmax-norm -> softmax; attention in-place over G. One wave/row.
__global__ __launch_bounds__(64)
void softmax_kernel(const float* __restrict__ w1, const float* __restrict__ b1,
                    const float* __restrict__ w2, const float* __restrict__ b2,
                    float* __restrict__ G, const float* __restrict__ S) {
    const int row = blockIdx.x;      // b*64 + c
    const int b = row >> 6, c = row & 63;
    const int e = threadIdx.x;

    float A = 0.f, Bc = 0.f, Be = 0.f, Cc = 0.f;
    #pragma unroll
    for (int j = 0; j < 8; ++j) {
        float a1 = w1[j], a2 = w2[j], q1 = b1[j], q2 = b2[j];
        A  += a1 * a2;
        Bc += a1 * q2;
        Be += q1 * a2;
        Cc += q1 * q2;
    }
    Cc *= (float)TT;

    float g  = G[(size_t)row * CC + e];
    float sc = S[b * CC + c];
    float se = S[b * CC + e];
    float energy = A * g + Bc * sc + Be * se + Cc;

    float mx = energy, mn = energy;
    #pragma unroll
    for (int off = 32; off; off >>= 1) {
        mx = fmaxf(mx, __shfl_xor(mx, off, 64));
        mn = fminf(mn, __shfl_xor(mn, off, 64));
    }
    float norm = (energy - mn) / (mx - mn + 1e-8f);
    float p = __expf(norm);
    float sum = p;
    #pragma unroll
    for (int off = 32; off; off >>= 1) sum += __shfl_xor(sum, off, 64);
    G[(size_t)row * CC + e] = p / sum;
}

// out[b,c,t] = gamma * sum_e att[b,e,c]*x[b,e,t] + x[b,c,t]
// 64c x 128t per block; 4c x 8t per thread; direct coalesced stores.
__global__ __launch_bounds__(256)
void apply_kernel(const float* __restrict__ x, const float* __restrict__ att,
                  const float* __restrict__ gamma, float* __restrict__ out) {
    __shared__ float As[CC * CC];    // 16 KB  As[e*64+c]
    __shared__ float xs[CC * TPB];   // 32 KB  xs[e*128+tl]
    const int b  = blockIdx.x / NT2;
    const int t0 = (blockIdx.x % NT2) * TPB;
    const int tid = threadIdx.x;
    const int tx = tid & 15, ty = tid >> 4;
    const float* attb = att + (size_t)b * CC * CC;
    const float* xb   = x + (size_t)b * CC * TT;

    for (int idx = tid; idx < CC * CC / 4; idx += 256)
        *(float4*)(As + 4 * idx) = *(const float4*)(attb + 4 * idx);
    for (int idx = tid; idx < CC * (TPB / 4); idx += 256) {
        int e = idx >> 5;            // TPB/4 == 32
        int p = idx & 31;
        int t = t0 + 4 * p;
        float4 v = make_float4(0.f, 0.f, 0.f, 0.f);
        if (t < TT) v = *(const float4*)(xb + e * TT + t);  // TT%4==0: all-or-none
        *(float4*)(xs + e * TPB + 4 * p) = v;
    }
    __syncthreads();

    // thread tile: c in [4ty,4ty+4), t-local in {4tx..4tx+3} u {64+4tx..64+4tx+3}
    float acc[4][8];
    #pragma unroll
    for (int i = 0; i < 4; ++i)
        #pragma unroll
        for (int j = 0; j < 8; ++j) acc[i][j] = 0.f;

    for (int e = 0; e < CC; ++e) {
        float4 m  = *(const float4*)(As + e * CC + 4 * ty);
        float4 v1 = *(const float4*)(xs + e * TPB + 4 * tx);
        float4 v2 = *(const float4*)(xs + e * TPB + 64 + 4 * tx);
        #pragma unroll
        for (int i = 0; i < 4; ++i) {
            float mi = (i == 0) ? m.x : (i == 1) ? m.y : (i == 2) ? m.z : m.w;
            acc[i][0] += mi * v1.x; acc[i][1] += mi * v1.y;
            acc[i][2] += mi * v1.z; acc[i][3] += mi * v1.w;
            acc[i][4] += mi * v2.x; acc[i][5] += mi * v2.y;
            acc[i][6] += mi * v2.z; acc[i][7] += mi * v2.w;
        }
    }

    const float gm = gamma[0];
    float* ob = out + (size_t)b * CC * TT;
    #pragma unroll
    for (int i = 0; i < 4; ++i) {
        const int c = 4 * ty + i;
        const int t1 = t0 + 4 * tx;
        const int t2 = t0 + 64 + 4 * tx;
        if (t1 < TT) {
            float4 xr = *(const float4*)(xs + c * TPB + 4 * tx);
            float4 r = make_float4(gm * acc[i][0] + xr.x, gm * acc[i][1] + xr.y,
                                   gm * acc[i][2] + xr.z, gm * acc[i][3] + xr.w);
            *(float4*)(ob + c * TT + t1) = r;
        }
        if (t2 < TT) {
            float4 xr = *(const float4*)(xs + c * TPB + 64 + 4 * tx);
            float4 r = make_float4(gm * acc[i][4] + xr.x, gm * acc[i][5] + xr.y,
                                   gm * acc[i][6] + xr.z, gm * acc[i][7] + xr.w);
            *(float4*)(ob + c * TT + t2) = r;
        }
    }
}

extern "C" void kernel_launch(void* const* d_in, const int* in_sizes, int n_in,
                              void* d_out, int out_size, void* d_ws, size_t ws_size,
                              hipStream_t stream) {
    const float* x  = (const float*)d_in[0];
    const float* w1 = (const float*)d_in[1];
    const float* b1 = (const float*)d_in[2];
    const float* w2 = (const float*)d_in[3];
    const float* b2 = (const float*)d_in[4];
    const float* gm = (const float*)d_in[5];
    float* out = (float*)d_out;
    float* G = (float*)d_ws;
    float* S = G + G_ELEMS;

    size_t zn = (G_ELEMS + S_ELEMS + 3) / 4;
    hipLaunchKernelGGL(zero_ws_kernel, dim3((zn + 1023) / 1024), dim3(256), 0, stream,
                       (float*)d_ws);
    hipLaunchKernelGGL(gram_kernel, dim3(BB * SLABS), dim3(256), 0, stream, x, G, S);
    hipLaunchKernelGGL(softmax_kernel, dim3(BB * CC), dim3(64), 0, stream,
                       w1, b1, w2, b2, G, S);
    hipLaunchKernelGGL(apply_kernel, dim3(BB * NT2), dim3(256), 0, stream,
                       x, G, gm, out);
}

// Round 3
// 169.291 us; speedup vs baseline: 2.0644x; 2.0644x over previous
//
#include <hip/hip_runtime.h>

#define BB 64
#define CC 64
#define TT 4000

// ---- gram (MFMA) geometry ----
#define SLABS 16
#define TSLAB 250            // 16*250 = 4000; staged padded to 256 t (16 k-steps of 16)
#define GP_PITCH 264         // shorts per LDS row: 256 staged + 8 pad (16B-aligned rows)

// ---- apply geometry (R2, proven) ----
#define TPB 128
#define NT2 ((TT + TPB - 1) / TPB)   // 32

// ws layout (floats): G_part[16][64][64][64] | S_part[16][64][64] | att[64][64][64]
#define GPART_ELEMS ((size_t)SLABS * BB * CC * CC)   // 4,194,304
#define SPART_ELEMS ((size_t)SLABS * BB * CC)        // 65,536
#define ATT_ELEMS   ((size_t)BB * CC * CC)           // 262,144

typedef short short8 __attribute__((ext_vector_type(8)));
typedef float f32x16 __attribute__((ext_vector_type(16)));

__device__ __forceinline__ short f2bf(float f) {
    unsigned u = __float_as_uint(f);
    u = (u + 0x7FFFu + ((u >> 16) & 1u)) >> 16;   // round-to-nearest-even
    return (short)u;
}

// G_part[s][b][r][c] = sum_{t in slab s} x[b][r][t]*x[b][c][t]   (non-atomic)
// S_part[s][b][c]    = sum_{t in slab s} x[b][c][t]              (non-atomic)
__global__ __launch_bounds__(256)
void gram_mfma(const float* __restrict__ x, float* __restrict__ G_part,
               float* __restrict__ S_part) {
    __shared__ short xs[CC * GP_PITCH];   // 33.8 KB bf16, row-major [row][t]
    __shared__ float sred[4 * 64];
    const int b    = blockIdx.x / SLABS;
    const int slab = blockIdx.x % SLABS;
    const int t0   = slab * TSLAB;
    const int tid  = threadIdx.x;
    const int lane = tid & 63;
    const int wave = tid >> 6;
    const float* xb = x + (size_t)b * CC * TT;

    // ---- stage fp32 -> bf16, coalesced 16B loads, 8B LDS writes (2-way, free) ----
    for (int i = tid; i < 64 * 64; i += 256) {
        int row = i >> 6, tq = i & 63;             // t_local = 4*tq, valid < 250
        float4 v = make_float4(0.f, 0.f, 0.f, 0.f);
        if (tq < 62) {
            v = *(const float4*)(xb + row * TT + t0 + 4 * tq);
        } else if (tq == 62) {                     // t_local 248,249 valid; 250,251 pad
            const float* p = xb + row * TT + t0 + 248;
            v.x = p[0]; v.y = p[1];
        }                                          // tq==63 -> pure zero pad (252..255)
        short4 sv;
        sv.x = f2bf(v.x); sv.y = f2bf(v.y); sv.z = f2bf(v.z); sv.w = f2bf(v.w);
        *(short4*)(xs + row * GP_PITCH + 4 * tq) = sv;
    }
    __syncthreads();

    // ---- S partials from staged bf16 (fp32 accumulate) ----
    {
        const short* base = xs + lane * GP_PITCH + 64 * wave;
        float s = 0.f;
        #pragma unroll
        for (int j = 0; j < 8; ++j) {
            uint4 u = *(const uint4*)(base + 8 * j);
            s += __uint_as_float(u.x << 16) + __uint_as_float(u.x & 0xFFFF0000u);
            s += __uint_as_float(u.y << 16) + __uint_as_float(u.y & 0xFFFF0000u);
            s += __uint_as_float(u.z << 16) + __uint_as_float(u.z & 0xFFFF0000u);
            s += __uint_as_float(u.w << 16) + __uint_as_float(u.w & 0xFFFF0000u);
        }
        sred[wave * 64 + lane] = s;
    }
    __syncthreads();
    if (tid < 64) {
        float s = sred[tid] + sred[64 + tid] + sred[128 + tid] + sred[192 + tid];
        S_part[(slab * BB + b) * CC + tid] = s;
    }

    // ---- MFMA: wave w owns 32x32 tile (r0,c0); A=B=rows of xs ----
    const int r0 = (wave >> 1) * 32, c0 = (wave & 1) * 32;
    const int m = lane & 31, half = lane >> 5;
    f32x16 acc;
    #pragma unroll
    for (int z = 0; z < 16; ++z) acc[z] = 0.f;
    #pragma unroll
    for (int ks = 0; ks < 16; ++ks) {
        const int k0 = ks * 16 + 8 * half;         // lane's contiguous 8 bf16 of k
        short8 av = *(const short8*)(xs + (r0 + m) * GP_PITCH + k0);
        short8 bv = *(const short8*)(xs + (c0 + m) * GP_PITCH + k0);
        acc = __builtin_amdgcn_mfma_f32_32x32x16_bf16(av, bv, acc, 0, 0, 0);
    }
    // C/D: col=lane&31, row=(reg&3)+8*(reg>>2)+4*(lane>>5)  (G symmetric: swap-safe)
    float* gp = G_part + ((size_t)slab * BB + b) * (CC * CC);
    #pragma unroll
    for (int r = 0; r < 16; ++r) {
        const int row = (r & 3) + 8 * (r >> 2) + 4 * half;
        gp[(r0 + row) * CC + (c0 + m)] = acc[r];
    }
}

// One block per batch: reduce G_part/S_part over slabs, energy, min-max norm,
// softmax; att[b][c][e] = attention[b,c,e] (same layout apply consumed in R2).
__global__ __launch_bounds__(256)
void softmax_fused(const float* __restrict__ w1, const float* __restrict__ b1,
                   const float* __restrict__ w2, const float* __restrict__ b2,
                   const float* __restrict__ G_part, const float* __restrict__ S_part,
                   float* __restrict__ att) {
    __shared__ float Es[64 * 65];            // pitch 65: conflict-free both phases
    __shared__ float Sb[64];
    __shared__ float red_mn[4 * 64], red_mx[4 * 64], red_sm[4 * 64];
    const int b   = blockIdx.x;
    const int tid = threadIdx.x;
    const int c = tid & 63, q = tid >> 6;

    for (int j = tid; j < 4096; j += 256) {
        float s = 0.f;
        #pragma unroll
        for (int sl = 0; sl < SLABS; ++sl)
            s += G_part[((size_t)sl * BB + b) * 4096 + j];
        Es[(j >> 6) * 65 + (j & 63)] = s;
    }
    if (tid < 64) {
        float s = 0.f;
        #pragma unroll
        for (int sl = 0; sl < SLABS; ++sl)
            s += S_part[(sl * BB + b) * CC + tid];
        Sb[tid] = s;
    }
    float A = 0.f, Bc = 0.f, Be = 0.f, Cc = 0.f;
    #pragma unroll
    for (int j = 0; j < 8; ++j) {
        float a1 = w1[j], a2 = w2[j], q1 = b1[j], q2 = b2[j];
        A += a1 * a2; Bc += a1 * q2; Be += q1 * a2; Cc += q1 * q2;
    }
    Cc *= (float)TT;
    __syncthreads();

    const float sc = Sb[c];
    float ev[16], mn = 1e30f, mx = -1e30f;
    #pragma unroll
    for (int i = 0; i < 16; ++i) {
        const int e = 16 * q + i;
        float en = A * Es[c * 65 + e] + Bc * sc + Be * Sb[e] + Cc;
        ev[i] = en;
        mn = fminf(mn, en); mx = fmaxf(mx, en);
    }
    red_mn[q * 64 + c] = mn; red_mx[q * 64 + c] = mx;
    __syncthreads();
    mn = fminf(fminf(red_mn[c], red_mn[64 + c]), fminf(red_mn[128 + c], red_mn[192 + c]));
    mx = fmaxf(fmaxf(red_mx[c], red_mx[64 + c]), fmaxf(red_mx[128 + c], red_mx[192 + c]));
    const float ninv = 1.f / (mx - mn + 1e-8f);
    float pv[16], ls = 0.f;
    #pragma unroll
    for (int i = 0; i < 16; ++i) {
        float p = __expf((ev[i] - mn) * ninv);
        pv[i] = p; ls += p;
    }
    red_sm[q * 64 + c] = ls;
    __syncthreads();
    const float rinv = 1.f / (red_sm[c] + red_sm[64 + c] + red_sm[128 + c] + red_sm[192 + c]);
    #pragma unroll
    for (int i = 0; i < 16; ++i) Es[c * 65 + 16 * q + i] = pv[i] * rinv;
    __syncthreads();
    float* ab = att + (size_t)b * 4096;
    for (int j = tid; j < 4096; j += 256)
        ab[j] = Es[(j >> 6) * 65 + (j & 63)];
}

// out[b,c,t] = gamma * sum_e att[b,e,c]*x[b,e,t] + x[b,c,t]   (R2 version, proven)
__global__ __launch_bounds__(256)
void apply_kernel(const float* __restrict__ x, const float* __restrict__ att,
                  const float* __restrict__ gamma, float* __restrict__ out) {
    __shared__ float As[CC * CC];    // 16 KB  As[e*64+c]
    __shared__ float xs[CC * TPB];   // 32 KB  xs[e*128+tl]
    const int b  = blockIdx.x / NT2;
    const int t0 = (blockIdx.x % NT2) * TPB;
    const int tid = threadIdx.x;
    const int tx = tid & 15, ty = tid >> 4;
    const float* attb = att + (size_t)b * CC * CC;
    const float* xb   = x + (size_t)b * CC * TT;

    for (int idx = tid; idx < CC * CC / 4; idx += 256)
        *(float4*)(As + 4 * idx) = *(const float4*)(attb + 4 * idx);
    for (int idx = tid; idx < CC * (TPB / 4); idx += 256) {
        int e = idx >> 5;
        int p = idx & 31;
        int t = t0 + 4 * p;
        float4 v = make_float4(0.f, 0.f, 0.f, 0.f);
        if (t < TT) v = *(const float4*)(xb + e * TT + t);
        *(float4*)(xs + e * TPB + 4 * p) = v;
    }
    __syncthreads();

    float acc[4][8];
    #pragma unroll
    for (int i = 0; i < 4; ++i)
        #pragma unroll
        for (int j = 0; j < 8; ++j) acc[i][j] = 0.f;

    for (int e = 0; e < CC; ++e) {
        float4 m  = *(const float4*)(As + e * CC + 4 * ty);
        float4 v1 = *(const float4*)(xs + e * TPB + 4 * tx);
        float4 v2 = *(const float4*)(xs + e * TPB + 64 + 4 * tx);
        #pragma unroll
        for (int i = 0; i < 4; ++i) {
            float mi = (i == 0) ? m.x : (i == 1) ? m.y : (i == 2) ? m.z : m.w;
            acc[i][0] += mi * v1.x; acc[i][1] += mi * v1.y;
            acc[i][2] += mi * v1.z; acc[i][3] += mi * v1.w;
            acc[i][4] += mi * v2.x; acc[i][5] += mi * v2.y;
            acc[i][6] += mi * v2.z; acc[i][7] += mi * v2.w;
        }
    }

    const float gm = gamma[0];
    float* ob = out + (size_t)b * CC * TT;
    #pragma unroll
    for (int i = 0; i < 4; ++i) {
        const int c = 4 * ty + i;
        const int t1 = t0 + 4 * tx;
        const int t2 = t0 + 64 + 4 * tx;
        if (t1 < TT) {
            float4 xr = *(const float4*)(xs + c * TPB + 4 * tx);
            float4 r = make_float4(gm * acc[i][0] + xr.x, gm * acc[i][1] + xr.y,
                                   gm * acc[i][2] + xr.z, gm * acc[i][3] + xr.w);
            *(float4*)(ob + c * TT + t1) = r;
        }
        if (t2 < TT) {
            float4 xr = *(const float4*)(xs + c * TPB + 64 + 4 * tx);
            float4 r = make_float4(gm * acc[i][4] + xr.x, gm * acc[i][5] + xr.y,
                                   gm * acc[i][6] + xr.z, gm * acc[i][7] + xr.w);
            *(float4*)(ob + c * TT + t2) = r;
        }
    }
}

extern "C" void kernel_launch(void* const* d_in, const int* in_sizes, int n_in,
                              void* d_out, int out_size, void* d_ws, size_t ws_size,
                              hipStream_t stream) {
    const float* x  = (const float*)d_in[0];
    const float* w1 = (const float*)d_in[1];
    const float* b1 = (const float*)d_in[2];
    const float* w2 = (const float*)d_in[3];
    const float* b2 = (const float*)d_in[4];
    const float* gm = (const float*)d_in[5];
    float* out = (float*)d_out;

    float* G_part = (float*)d_ws;                  // 16 MB
    float* S_part = G_part + GPART_ELEMS;          // 256 KB
    float* att    = S_part + SPART_ELEMS;          // 1 MB

    hipLaunchKernelGGL(gram_mfma, dim3(BB * SLABS), dim3(256), 0, stream,
                       x, G_part, S_part);
    hipLaunchKernelGGL(softmax_fused, dim3(BB), dim3(256), 0, stream,
                       w1, b1, w2, b2, G_part, S_part, att);
    hipLaunchKernelGGL(apply_kernel, dim3(BB * NT2), dim3(256), 0, stream,
                       x, att, gm, out);
}

// Round 4
// 167.160 us; speedup vs baseline: 2.0907x; 1.0127x over previous
//
#include <hip/hip_runtime.h>

#define BB 64
#define CC 64
#define TT 4000

// ---- gram (MFMA) geometry ----
#define SLABS 16
#define TSLAB 250            // staged padded to 256 t (32 chunks of 8 bf16)
#define GP_PITCH 264         // shorts per LDS row (16B-aligned rows, chunk 32 = pad)

// ---- apply geometry ----
#define TPB 128
#define NT2 ((TT + TPB - 1) / TPB)   // 32
#define XPITCH 132           // floats per xs row (16B aligned)
#define APITCH 72            // shorts per attL row (16B aligned)

// ws layout (floats): G_part[16][64][64][64] | S_part[16][64][64] | attG[64][64][64]
#define GPART_ELEMS ((size_t)SLABS * BB * CC * CC)
#define SPART_ELEMS ((size_t)SLABS * BB * CC)

typedef short short8 __attribute__((ext_vector_type(8)));
typedef float f32x16 __attribute__((ext_vector_type(16)));

__device__ __forceinline__ short f2bf(float f) {
    unsigned u = __float_as_uint(f);
    u = (u + 0x7FFFu + ((u >> 16) & 1u)) >> 16;   // round-to-nearest-even
    return (short)u;
}
__device__ __forceinline__ float bfpair(unsigned u) {   // sum of 2 packed bf16
    return __uint_as_float(u << 16) + __uint_as_float(u & 0xFFFF0000u);
}

// G_part[s][b][r][c] = sum_{t in slab} x[b][r][t]*x[b][c][t]; S_part likewise.
// LDS chunk-XOR swizzle: 8-short chunk c of row r lives at chunk (c ^ (r&7)).
__global__ __launch_bounds__(256)
void gram_mfma(const float* __restrict__ x, float* __restrict__ G_part,
               float* __restrict__ S_part) {
    __shared__ short xs[CC * GP_PITCH];   // 33.8 KB bf16
    __shared__ float sred[4 * 64];
    const int b    = blockIdx.x / SLABS;
    const int slab = blockIdx.x % SLABS;
    const int t0   = slab * TSLAB;
    const int tid  = threadIdx.x;
    const int lane = tid & 63;
    const int wave = tid >> 6;
    const float* xb = x + (size_t)b * CC * TT;

    // stage fp32 -> bf16, coalesced 16B global loads, swizzled short4 LDS writes
    for (int i = tid; i < 64 * 64; i += 256) {
        int row = i >> 6, tq = i & 63;             // t_local = 4*tq
        float4 v = make_float4(0.f, 0.f, 0.f, 0.f);
        if (tq < 62) {
            v = *(const float4*)(xb + row * TT + t0 + 4 * tq);
        } else if (tq == 62) {
            const float* p = xb + row * TT + t0 + 248;
            v.x = p[0]; v.y = p[1];
        }
        short4 sv;
        sv.x = f2bf(v.x); sv.y = f2bf(v.y); sv.z = f2bf(v.z); sv.w = f2bf(v.w);
        int pc = (tq >> 1) ^ (row & 7);            // swizzled chunk
        *(short4*)(xs + row * GP_PITCH + pc * 8 + (tq & 1) * 4) = sv;
    }
    __syncthreads();

    // S partials: b64 reads (conflict-free under the swizzle), fp32 accumulate
    {
        const short* rowp = xs + lane * GP_PITCH;
        float s = 0.f;
        #pragma unroll
        for (int j = 0; j < 8; ++j) {
            int pc = (wave * 8 + j) ^ (lane & 7);
            uint2 u0 = *(const uint2*)(rowp + pc * 8);
            uint2 u1 = *(const uint2*)(rowp + pc * 8 + 4);
            s += bfpair(u0.x) + bfpair(u0.y) + bfpair(u1.x) + bfpair(u1.y);
        }
        sred[wave * 64 + lane] = s;
    }
    __syncthreads();
    if (tid < 64) {
        float s = sred[tid] + sred[64 + tid] + sred[128 + tid] + sred[192 + tid];
        S_part[(slab * BB + b) * CC + tid] = s;
    }

    // MFMA: wave owns 32x32 tile (r0,c0)
    const int r0 = (wave >> 1) * 32, c0 = (wave & 1) * 32;
    const int m = lane & 31, half = lane >> 5;
    f32x16 acc;
    #pragma unroll
    for (int z = 0; z < 16; ++z) acc[z] = 0.f;
    #pragma unroll
    for (int ks = 0; ks < 16; ++ks) {
        const int ck = ks * 2 + half;              // logical 8-short chunk of k
        short8 av = *(const short8*)(xs + (r0 + m) * GP_PITCH + (ck ^ (m & 7)) * 8);
        short8 bv = *(const short8*)(xs + (c0 + m) * GP_PITCH + (ck ^ (m & 7)) * 8);
        acc = __builtin_amdgcn_mfma_f32_32x32x16_bf16(av, bv, acc, 0, 0, 0);
    }
    float* gp = G_part + ((size_t)slab * BB + b) * (CC * CC);
    #pragma unroll
    for (int r = 0; r < 16; ++r) {
        const int row = (r & 3) + 8 * (r >> 2) + 4 * half;
        gp[(r0 + row) * CC + (c0 + m)] = acc[r];
    }
}

// One block/batch: slab-reduce, energy, min-max norm, softmax.
// Emits attG[b][c][e] = P[e][c]  (P = attention row-softmax) -- the A-operand
// layout apply_mfma wants. Pitch-65 Es is conflict-free for row AND col access.
__global__ __launch_bounds__(256)
void softmax_fused(const float* __restrict__ w1, const float* __restrict__ b1,
                   const float* __restrict__ w2, const float* __restrict__ b2,
                   const float* __restrict__ G_part, const float* __restrict__ S_part,
                   float* __restrict__ attG) {
    __shared__ float Es[64 * 65];
    __shared__ float Sb[64];
    __shared__ float red_mn[4 * 64], red_mx[4 * 64], red_sm[4 * 64];
    const int b   = blockIdx.x;
    const int tid = threadIdx.x;
    const int c = tid & 63, q = tid >> 6;

    for (int j = tid; j < 4096; j += 256) {
        float s = 0.f;
        #pragma unroll
        for (int sl = 0; sl < SLABS; ++sl)
            s += G_part[((size_t)sl * BB + b) * 4096 + j];
        Es[(j >> 6) * 65 + (j & 63)] = s;
    }
    if (tid < 64) {
        float s = 0.f;
        #pragma unroll
        for (int sl = 0; sl < SLABS; ++sl)
            s += S_part[(sl * BB + b) * CC + tid];
        Sb[tid] = s;
    }
    float A = 0.f, Bc = 0.f, Be = 0.f, Cc = 0.f;
    #pragma unroll
    for (int j = 0; j < 8; ++j) {
        float a1 = w1[j], a2 = w2[j], q1 = b1[j], q2 = b2[j];
        A += a1 * a2; Bc += a1 * q2; Be += q1 * a2; Cc += q1 * q2;
    }
    Cc *= (float)TT;
    __syncthreads();

    const float sc = Sb[c];
    float ev[16], mn = 1e30f, mx = -1e30f;
    #pragma unroll
    for (int i = 0; i < 16; ++i) {
        const int e = 16 * q + i;
        float en = A * Es[c * 65 + e] + Bc * sc + Be * Sb[e] + Cc;
        ev[i] = en;
        mn = fminf(mn, en); mx = fmaxf(mx, en);
    }
    red_mn[q * 64 + c] = mn; red_mx[q * 64 + c] = mx;
    __syncthreads();
    mn = fminf(fminf(red_mn[c], red_mn[64 + c]), fminf(red_mn[128 + c], red_mn[192 + c]));
    mx = fmaxf(fmaxf(red_mx[c], red_mx[64 + c]), fmaxf(red_mx[128 + c], red_mx[192 + c]));
    const float ninv = 1.f / (mx - mn + 1e-8f);
    float pv[16], ls = 0.f;
    #pragma unroll
    for (int i = 0; i < 16; ++i) {
        float p = __expf((ev[i] - mn) * ninv);
        pv[i] = p; ls += p;
    }
    red_sm[q * 64 + c] = ls;
    __syncthreads();
    const float rinv = 1.f / (red_sm[c] + red_sm[64 + c] + red_sm[128 + c] + red_sm[192 + c]);
    #pragma unroll
    for (int i = 0; i < 16; ++i) Es[c * 65 + 16 * q + i] = pv[i] * rinv;   // Es[c][e]=P[c][e]
    __syncthreads();
    float* ab = attG + (size_t)b * 4096;
    for (int j = tid; j < 4096; j += 256) {
        int cc = j >> 6, ee = j & 63;
        ab[j] = Es[ee * 65 + cc];                  // attG[cc][ee] = P[ee][cc]
    }
}

// out[b,c,t] = gamma * sum_e P[e,c]*x[e,t] + x[b,c,t]  via bf16 MFMA.
// A = attG rows (bf16 in LDS), B-frags built from fp32 x tile (also residual).
__global__ __launch_bounds__(256)
void apply_mfma(const float* __restrict__ x, const float* __restrict__ attG,
                const float* __restrict__ gamma, float* __restrict__ out) {
    __shared__ float xs[CC * XPITCH];   // 33.8 KB fp32 [e][t]
    __shared__ short al[CC * APITCH];   // 9.2 KB bf16  [c][e]
    const int b  = blockIdx.x / NT2;
    const int t0 = (blockIdx.x % NT2) * TPB;
    const int tid = threadIdx.x;
    const int lane = tid & 63, wave = tid >> 6;
    const float* xb = x + (size_t)b * CC * TT;
    const float* ab = attG + (size_t)b * CC * CC;

    for (int i = tid; i < CC * (TPB / 4); i += 256) {
        int e = i >> 5, p = i & 31;
        int t = t0 + 4 * p;
        float4 v = make_float4(0.f, 0.f, 0.f, 0.f);
        if (t < TT) v = *(const float4*)(xb + e * TT + t);
        *(float4*)(xs + e * XPITCH + 4 * p) = v;
    }
    for (int i = tid; i < CC * CC / 4; i += 256) {
        int c = i >> 4, qq = i & 15;
        float4 v = *(const float4*)(ab + c * CC + 4 * qq);
        short4 sv;
        sv.x = f2bf(v.x); sv.y = f2bf(v.y); sv.z = f2bf(v.z); sv.w = f2bf(v.w);
        *(short4*)(al + c * APITCH + 4 * qq) = sv;
    }
    __syncthreads();

    const int m = lane & 31, half = lane >> 5;
    const int c0 = (wave & 1) * 32;
    const int tb = (wave >> 1) * 64;
    f32x16 acc0, acc1;
    #pragma unroll
    for (int z = 0; z < 16; ++z) { acc0[z] = 0.f; acc1[z] = 0.f; }

    #pragma unroll
    for (int ks = 0; ks < 4; ++ks) {
        short8 av = *(const short8*)(al + (c0 + m) * APITCH + ks * 16 + 8 * half);
        const int eb = ks * 16 + 8 * half;
        short8 bv0, bv1;
        #pragma unroll
        for (int j = 0; j < 8; ++j) {
            bv0[j] = f2bf(xs[(eb + j) * XPITCH + tb + m]);
            bv1[j] = f2bf(xs[(eb + j) * XPITCH + tb + 32 + m]);
        }
        acc0 = __builtin_amdgcn_mfma_f32_32x32x16_bf16(av, bv0, acc0, 0, 0, 0);
        acc1 = __builtin_amdgcn_mfma_f32_32x32x16_bf16(av, bv1, acc1, 0, 0, 0);
    }

    const float gm = gamma[0];
    float* ob = out + (size_t)b * CC * TT;
    #pragma unroll
    for (int r = 0; r < 16; ++r) {
        const int row = (r & 3) + 8 * (r >> 2) + 4 * half;
        const int c = c0 + row;
        const int tl0 = tb + m, tl1 = tb + 32 + m;
        const int tg0 = t0 + tl0, tg1 = t0 + tl1;
        if (tg0 < TT) ob[c * TT + tg0] = gm * acc0[r] + xs[c * XPITCH + tl0];
        if (tg1 < TT) ob[c * TT + tg1] = gm * acc1[r] + xs[c * XPITCH + tl1];
    }
}

extern "C" void kernel_launch(void* const* d_in, const int* in_sizes, int n_in,
                              void* d_out, int out_size, void* d_ws, size_t ws_size,
                              hipStream_t stream) {
    const float* x  = (const float*)d_in[0];
    const float* w1 = (const float*)d_in[1];
    const float* b1 = (const float*)d_in[2];
    const float* w2 = (const float*)d_in[3];
    const float* b2 = (const float*)d_in[4];
    const float* gm = (const float*)d_in[5];
    float* out = (float*)d_out;

    float* G_part = (float*)d_ws;
    float* S_part = G_part + GPART_ELEMS;
    float* attG   = S_part + SPART_ELEMS;

    hipLaunchKernelGGL(gram_mfma, dim3(BB * SLABS), dim3(256), 0, stream,
                       x, G_part, S_part);
    hipLaunchKernelGGL(softmax_fused, dim3(BB), dim3(256), 0, stream,
                       w1, b1, w2, b2, G_part, S_part, attG);
    hipLaunchKernelGGL(apply_mfma, dim3(BB * NT2), dim3(256), 0, stream,
                       x, attG, gm, out);
}